// Round 1
// baseline (2353.192 us; speedup 1.0000x reference)
//
#include <hip/hip_runtime.h>

typedef short bf16x8 __attribute__((ext_vector_type(8)));
typedef short short4v __attribute__((ext_vector_type(4)));
typedef float f32x4 __attribute__((ext_vector_type(4)));

#define SCALE_ATTN 0.08838834764831845f

__device__ inline short f2bs(float f) {
    unsigned u = __builtin_bit_cast(unsigned, f);
    unsigned r = (u + 0x7fffu + ((u >> 16) & 1u)) >> 16;
    return (short)(unsigned short)r;
}
__device__ inline float b2f(short s) {
    unsigned u = ((unsigned)(unsigned short)s) << 16;
    return __builtin_bit_cast(float, u);
}
__device__ inline void pack_w(const float4& a, const float4& b, bf16x8& p) {
    p[0] = f2bs(a.x); p[1] = f2bs(a.y); p[2] = f2bs(a.z); p[3] = f2bs(a.w);
    p[4] = f2bs(b.x); p[5] = f2bs(b.y); p[6] = f2bs(b.z); p[7] = f2bs(b.w);
}

// ---------------------------------------------------------------------------
// fused add + RMSNorm.  If Rin: sum = X+Rin, write sum (f32) to Rout.
// Writes bf16 normalized output to Hout.  One block per row of 4096.
// ---------------------------------------------------------------------------
__global__ __launch_bounds__(256)
void add_rmsnorm_kernel(const float* __restrict__ X, const float* __restrict__ Rin,
                        const float* __restrict__ w, float* __restrict__ Rout,
                        short* __restrict__ Hout)
{
    const int tid = threadIdx.x;
    const long base = (long)blockIdx.x << 12;
    float v[16];
    float ss = 0.f;
#pragma unroll
    for (int p = 0; p < 4; ++p) {
        const int idx = (p << 10) + (tid << 2);
        float4 a = *(const float4*)(X + base + idx);
        if (Rin != nullptr) {
            float4 b = *(const float4*)(Rin + base + idx);
            a.x += b.x; a.y += b.y; a.z += b.z; a.w += b.w;
        }
        v[p*4+0] = a.x; v[p*4+1] = a.y; v[p*4+2] = a.z; v[p*4+3] = a.w;
        ss += a.x*a.x + a.y*a.y + a.z*a.z + a.w*a.w;
    }
#pragma unroll
    for (int dd = 1; dd < 64; dd <<= 1) ss += __shfl_xor(ss, dd);
    __shared__ float red[4];
    if ((tid & 63) == 0) red[tid >> 6] = ss;
    __syncthreads();
    const float tot = red[0] + red[1] + red[2] + red[3];
    const float rstd = rsqrtf(tot * (1.0f / 4096.0f) + 1e-5f);
#pragma unroll
    for (int p = 0; p < 4; ++p) {
        const int idx = (p << 10) + (tid << 2);
        if (Rout != nullptr) {
            float4 b; b.x = v[p*4+0]; b.y = v[p*4+1]; b.z = v[p*4+2]; b.w = v[p*4+3];
            *(float4*)(Rout + base + idx) = b;
        }
        float4 wv4 = *(const float4*)(w + idx);
        short4v hb;
        hb[0] = f2bs(v[p*4+0] * rstd * wv4.x);
        hb[1] = f2bs(v[p*4+1] * rstd * wv4.y);
        hb[2] = f2bs(v[p*4+2] * rstd * wv4.z);
        hb[3] = f2bs(v[p*4+3] * rstd * wv4.w);
        *(short4v*)(Hout + base + idx) = hb;
    }
}

// ---------------------------------------------------------------------------
// GEMM: C[M,N] = A[M,K](bf16) * W[N,K](f32, converted to bf16 in staging)
// 128x128 tile, BK=32, 4 waves of 64x64, mfma 16x16x32 bf16.
// EPI 0: f32 store.  EPI 1: f32 store + resid add.  EPI 2: bf16 store.
// ---------------------------------------------------------------------------
template<int EPI>
__global__ __launch_bounds__(256)
void gemm_kernel(const short* __restrict__ A, const float* __restrict__ W,
                 float* __restrict__ Cf, short* __restrict__ Cb,
                 const float* __restrict__ resid, int N, int K)
{
    __shared__ short As[2][128][40];
    __shared__ short Ws[2][128][40];
    const int tid  = threadIdx.x;
    const int lane = tid & 63;
    const int wv   = tid >> 6;
    const int wr   = (wv >> 1) << 6;
    const int wc   = (wv & 1) << 6;
    const int l15  = lane & 15;
    const int l4e  = (lane >> 4) << 3;    // 0,8,16,24
    const long row0 = (long)blockIdx.y << 7;
    const long col0 = (long)blockIdx.x << 7;

    const int srow = tid >> 1;
    const int sk   = (tid & 1) << 4;      // 0 or 16
    const short* aptr = A + (row0 + srow) * K + sk;
    const float* wptr = W + (col0 + srow) * K + sk;

    f32x4 acc[4][4];
#pragma unroll
    for (int i = 0; i < 4; ++i)
#pragma unroll
        for (int j = 0; j < 4; ++j) acc[i][j] = (f32x4){0.f,0.f,0.f,0.f};

    const int nk = K >> 5;

    bf16x8 a0 = *(const bf16x8*)(aptr);
    bf16x8 a1 = *(const bf16x8*)(aptr + 8);
    float4 w0 = *(const float4*)(wptr);
    float4 w1 = *(const float4*)(wptr + 4);
    float4 w2 = *(const float4*)(wptr + 8);
    float4 w3 = *(const float4*)(wptr + 12);
    {
        *(bf16x8*)&As[0][srow][sk]     = a0;
        *(bf16x8*)&As[0][srow][sk + 8] = a1;
        bf16x8 p0, p1;
        pack_w(w0, w1, p0); pack_w(w2, w3, p1);
        *(bf16x8*)&Ws[0][srow][sk]     = p0;
        *(bf16x8*)&Ws[0][srow][sk + 8] = p1;
    }
    __syncthreads();

    for (int kt = 0; kt < nk; ++kt) {
        const int buf = kt & 1;
        if (kt + 1 < nk) {
            const short* ap = aptr + ((long)(kt + 1) << 5);
            const float* wp = wptr + ((long)(kt + 1) << 5);
            a0 = *(const bf16x8*)(ap);
            a1 = *(const bf16x8*)(ap + 8);
            w0 = *(const float4*)(wp);
            w1 = *(const float4*)(wp + 4);
            w2 = *(const float4*)(wp + 8);
            w3 = *(const float4*)(wp + 12);
        }
        bf16x8 af[4], bfr[4];
#pragma unroll
        for (int i = 0; i < 4; ++i)
            af[i] = *(const bf16x8*)&As[buf][wr + i*16 + l15][l4e];
#pragma unroll
        for (int j = 0; j < 4; ++j)
            bfr[j] = *(const bf16x8*)&Ws[buf][wc + j*16 + l15][l4e];
#pragma unroll
        for (int i = 0; i < 4; ++i)
#pragma unroll
            for (int j = 0; j < 4; ++j)
                acc[i][j] = __builtin_amdgcn_mfma_f32_16x16x32_bf16(af[i], bfr[j], acc[i][j], 0, 0, 0);
        if (kt + 1 < nk) {
            const int nb = buf ^ 1;
            *(bf16x8*)&As[nb][srow][sk]     = a0;
            *(bf16x8*)&As[nb][srow][sk + 8] = a1;
            bf16x8 p0, p1;
            pack_w(w0, w1, p0); pack_w(w2, w3, p1);
            *(bf16x8*)&Ws[nb][srow][sk]     = p0;
            *(bf16x8*)&Ws[nb][srow][sk + 8] = p1;
        }
        __syncthreads();
    }

#pragma unroll
    for (int i = 0; i < 4; ++i) {
#pragma unroll
        for (int j = 0; j < 4; ++j) {
            const long gr = row0 + wr + i*16 + ((lane >> 4) << 2);
            const long gc = col0 + wc + j*16 + l15;
#pragma unroll
            for (int r = 0; r < 4; ++r) {
                const float v = acc[i][j][r];
                const long idx = (gr + r) * N + gc;
                if (EPI == 0)      Cf[idx] = v;
                else if (EPI == 1) Cf[idx] = v + resid[idx];
                else               Cb[idx] = f2bs(v);
            }
        }
    }
}

// ---------------------------------------------------------------------------
// RoPE: reads qkv f32 [S,6144]; writes roped q (bf16 [S,32,128]) and
// k (bf16 [S,8,128]).  grid (40, S), block 128.
// ---------------------------------------------------------------------------
__global__ __launch_bounds__(128)
void rope_kernel(const int* __restrict__ pos, const float* __restrict__ qkv,
                 short* __restrict__ Qo, short* __restrict__ Ko)
{
    const int h = blockIdx.x;
    const int s = blockIdx.y;
    const int d = threadIdx.x;
    const int j = d & 63;
    const float p = (float)pos[s];
    const float invf = __expf((float)j * -0.20503692895f);  // ln(5e5)/64
    float sn, cs;
    __sincosf(p * invf, &sn, &cs);
    const long base = (long)s * 6144 + h * 128;
    const float x1 = qkv[base + j];
    const float x2 = qkv[base + 64 + j];
    const float outv = (d < 64) ? (x1 * cs - x2 * sn) : (x2 * cs + x1 * sn);
    const short ob = f2bs(outv);
    if (h < 32) Qo[(long)s * 4096 + h * 128 + d] = ob;
    else        Ko[(long)s * 1024 + (h - 32) * 128 + d] = ob;
}

// ---------------------------------------------------------------------------
// V transpose: qkv f32 v-part [S,8,128] -> Vt bf16 [8][128][S]
// grid (S/64, 8), block 256.
// ---------------------------------------------------------------------------
__global__ __launch_bounds__(256)
void vtrans_kernel(const float* __restrict__ qkv, short* __restrict__ Vt)
{
    __shared__ short tile[64][136];
    const int tid = threadIdx.x;
    const int s0 = blockIdx.x << 6;
    const int h = blockIdx.y;
    {
        const int srow = tid >> 2;
        const int c0 = (tid & 3) << 5;
        const float* src = qkv + (long)(s0 + srow) * 6144 + 5120 + h * 128 + c0;
#pragma unroll
        for (int m = 0; m < 8; ++m) {
            float4 f = *(const float4*)(src + (m << 2));
            tile[srow][c0 + (m << 2) + 0] = f2bs(f.x);
            tile[srow][c0 + (m << 2) + 1] = f2bs(f.y);
            tile[srow][c0 + (m << 2) + 2] = f2bs(f.z);
            tile[srow][c0 + (m << 2) + 3] = f2bs(f.w);
        }
    }
    __syncthreads();
    {
        const int d = tid >> 1;
        const int sc = (tid & 1) << 5;
        short* dst = Vt + ((long)h * 128 + d) * 2048 + s0 + sc;
#pragma unroll
        for (int m = 0; m < 4; ++m) {
            bf16x8 v;
#pragma unroll
            for (int e = 0; e < 8; ++e) v[e] = tile[sc + (m << 3) + e][d];
            *(bf16x8*)(dst + (m << 3)) = v;
        }
    }
}

// ---------------------------------------------------------------------------
// Flash attention (causal, GQA rep=4).  grid (S/64 qtiles, 32 heads), 256 thr.
// 4 waves x 16 q-rows each; KV tiles of 64; XOR-swizzled LDS.
// ---------------------------------------------------------------------------
__global__ __launch_bounds__(256)
void flash_kernel(const short* __restrict__ Qg, const short* __restrict__ Kg,
                  const short* __restrict__ Vtg, short* __restrict__ Ctx)
{
    __shared__ short Qs[64 * 128];
    __shared__ short Ks[64 * 128];
    __shared__ short Vs[128 * 64];
    __shared__ short Ps[4 * 16 * 64];

    const int tid  = threadIdx.x;
    const int lane = tid & 63;
    const int wv   = tid >> 6;
    const int l15  = lane & 15;
    const int l4e  = (lane >> 4) << 3;
    const int qt   = blockIdx.x;
    const int head = blockIdx.y;
    const int q0   = qt << 6;
    const int kvh  = head >> 2;

    {   // stage Q (swizzled)
        const int row = tid >> 2;
        const int c0 = (tid & 3) << 5;
        const short* src = Qg + (long)(q0 + row) * 4096 + head * 128 + c0;
        const int sw = (row & 7) << 3;
#pragma unroll
        for (int m = 0; m < 4; ++m) {
            bf16x8 v = *(const bf16x8*)(src + (m << 3));
            *(bf16x8*)&Qs[row * 128 + ((c0 + (m << 3)) ^ sw)] = v;
        }
    }

    float mrow[4], lrow[4];
    f32x4 o[8];
#pragma unroll
    for (int r = 0; r < 4; ++r) { mrow[r] = -__builtin_inff(); lrow[r] = 0.f; }
#pragma unroll
    for (int d = 0; d < 8; ++d) o[d] = (f32x4){0.f,0.f,0.f,0.f};

    for (int t = 0; t <= qt; ++t) {
        const int kv0 = t << 6;
        __syncthreads();
        {   // stage K
            const int row = tid >> 2;
            const int c0 = (tid & 3) << 5;
            const short* src = Kg + (long)(kv0 + row) * 1024 + kvh * 128 + c0;
            const int sw = (row & 7) << 3;
#pragma unroll
            for (int m = 0; m < 4; ++m) {
                bf16x8 v = *(const bf16x8*)(src + (m << 3));
                *(bf16x8*)&Ks[row * 128 + ((c0 + (m << 3)) ^ sw)] = v;
            }
        }
        {   // stage Vt
            const int d = tid >> 1;
            const int c0 = (tid & 1) << 5;
            const short* src = Vtg + ((long)kvh * 128 + d) * 2048 + kv0 + c0;
            const int sw = (d & 7) << 3;
#pragma unroll
            for (int m = 0; m < 4; ++m) {
                bf16x8 v = *(const bf16x8*)(src + (m << 3));
                *(bf16x8*)&Vs[d * 64 + ((c0 + (m << 3)) ^ sw)] = v;
            }
        }
        __syncthreads();

        // QK^T : 16 q-rows x 64 kv-cols per wave
        bf16x8 qa[4];
        {
            const int qrow = (wv << 4) + l15;
            const int sw = (qrow & 7) << 3;
#pragma unroll
            for (int kk = 0; kk < 4; ++kk)
                qa[kk] = *(const bf16x8*)&Qs[qrow * 128 + ((l4e + (kk << 5)) ^ sw)];
        }
        f32x4 sacc[4];
#pragma unroll
        for (int j = 0; j < 4; ++j) {
            sacc[j] = (f32x4){0.f,0.f,0.f,0.f};
            const int krow = (j << 4) + l15;
            const int sw = (krow & 7) << 3;
#pragma unroll
            for (int kk = 0; kk < 4; ++kk) {
                bf16x8 kb8 = *(const bf16x8*)&Ks[krow * 128 + ((l4e + (kk << 5)) ^ sw)];
                sacc[j] = __builtin_amdgcn_mfma_f32_16x16x32_bf16(qa[kk], kb8, sacc[j], 0, 0, 0);
            }
        }

        // online softmax (rows live in 16-lane groups)
#pragma unroll
        for (int ri = 0; ri < 4; ++ri) {
            const int grow = q0 + (wv << 4) + ((lane >> 4) << 2) + ri;
            float sv[4];
#pragma unroll
            for (int j = 0; j < 4; ++j) {
                float s = sacc[j][ri] * SCALE_ATTN;
                const int col = kv0 + (j << 4) + l15;
                sv[j] = (col > grow) ? -1e30f : s;
            }
            float mx = fmaxf(fmaxf(sv[0], sv[1]), fmaxf(sv[2], sv[3]));
#pragma unroll
            for (int dd = 1; dd < 16; dd <<= 1) mx = fmaxf(mx, __shfl_xor(mx, dd));
            const float mnew = fmaxf(mrow[ri], mx);
            const float alpha = __expf(mrow[ri] - mnew);
            mrow[ri] = mnew;
            float psum = 0.f;
            short pb[4];
#pragma unroll
            for (int j = 0; j < 4; ++j) {
                float p = __expf(sv[j] - mnew);
                psum += p;
                pb[j] = f2bs(p);
            }
            lrow[ri] = lrow[ri] * alpha + psum;
#pragma unroll
            for (int d = 0; d < 8; ++d) o[d][ri] *= alpha;
            const int prow = ((lane >> 4) << 2) + ri;
            const int sw = (prow & 7) << 3;
#pragma unroll
            for (int j = 0; j < 4; ++j)
                Ps[(wv << 10) + prow * 64 + ((((j << 4) + l15)) ^ sw)] = pb[j];
        }

        // PV : P(16x64) x V(64x128)
        bf16x8 pa0, pa1;
        {
            const int prow = l15;
            const int sw = (prow & 7) << 3;
            pa0 = *(const bf16x8*)&Ps[(wv << 10) + prow * 64 + (l4e ^ sw)];
            pa1 = *(const bf16x8*)&Ps[(wv << 10) + prow * 64 + ((l4e + 32) ^ sw)];
        }
#pragma unroll
        for (int fd = 0; fd < 8; ++fd) {
            const int drow = (fd << 4) + l15;
            const int sw = (drow & 7) << 3;
            bf16x8 v0 = *(const bf16x8*)&Vs[drow * 64 + (l4e ^ sw)];
            bf16x8 v1 = *(const bf16x8*)&Vs[drow * 64 + ((l4e + 32) ^ sw)];
            o[fd] = __builtin_amdgcn_mfma_f32_16x16x32_bf16(pa0, v0, o[fd], 0, 0, 0);
            o[fd] = __builtin_amdgcn_mfma_f32_16x16x32_bf16(pa1, v1, o[fd], 0, 0, 0);
        }
    }

    float inv[4];
#pragma unroll
    for (int ri = 0; ri < 4; ++ri) {
        float ls = lrow[ri];
#pragma unroll
        for (int dd = 1; dd < 16; dd <<= 1) ls += __shfl_xor(ls, dd);
        inv[ri] = 1.0f / ls;
    }
#pragma unroll
    for (int fd = 0; fd < 8; ++fd)
#pragma unroll
        for (int ri = 0; ri < 4; ++ri) {
            const long row = q0 + (wv << 4) + ((lane >> 4) << 2) + ri;
            Ctx[row * 4096 + head * 128 + (fd << 4) + l15] = f2bs(o[fd][ri] * inv[ri]);
        }
}

// ---------------------------------------------------------------------------
// SiLU(gate)*up : gu bf16 [S, 28672] -> hm bf16 [S, 14336]
// grid (7, S), block 256, 8 elems/thread.
// ---------------------------------------------------------------------------
__global__ __launch_bounds__(256)
void silu_kernel(const short* __restrict__ gu, short* __restrict__ hm)
{
    const int s = blockIdx.y;
    const int j = ((blockIdx.x << 8) + threadIdx.x) << 3;
    const short* g = gu + (long)s * 28672 + j;
    bf16x8 gv = *(const bf16x8*)g;
    bf16x8 uv = *(const bf16x8*)(g + 14336);
    bf16x8 ov;
#pragma unroll
    for (int e = 0; e < 8; ++e) {
        const float gf = b2f(gv[e]);
        const float uf = b2f(uv[e]);
        const float r = gf / (1.f + __expf(-gf)) * uf;
        ov[e] = f2bs(r);
    }
    *(bf16x8*)(hm + (long)s * 14336 + j) = ov;
}

// ---------------------------------------------------------------------------
extern "C" void kernel_launch(void* const* d_in, const int* in_sizes, int n_in,
                              void* d_out, int out_size, void* d_ws, size_t ws_size,
                              hipStream_t stream)
{
    const int*   positions = (const int*)d_in[0];
    const float* hidden    = (const float*)d_in[1];
    const float* residual  = (const float*)d_in[2];
    const float* w_qkv     = (const float*)d_in[3];
    const float* w_o       = (const float*)d_in[4];
    const float* w_gu      = (const float*)d_in[5];
    const float* w_down    = (const float*)d_in[6];
    const float* w_ln1     = (const float*)d_in[7];
    const float* w_ln2     = (const float*)d_in[8];

    float* out_f   = (float*)d_out;              // [2048,4096] final output
    float* resid2  = out_f + 8388608;            // [2048,4096] residual output
    float* resid1  = out_f;                      // scratch: dead before down-GEMM writes

    char* wsb = (char*)d_ws;
    short* h1     = (short*)(wsb + 0);           // 16.8 MB (dead after qkv gemm)
    short* ctx    = (short*)(wsb + 0);           // reuse
    float* qkvbuf = (float*)(wsb + 16777216);    // 50.3 MB (dead after rope/vtrans)
    short* hm     = (short*)(wsb + 16777216);    // reuse (58.7 MB)
    short* qb     = (short*)(wsb + 67108864);    // 16.8 MB
    short* kb     = (short*)(wsb + 83886080);    // 4.2 MB
    short* vt     = (short*)(wsb + 88080384);    // 4.2 MB
    short* h2     = (short*)(wsb + 92274688);    // 16.8 MB
    short* gu     = (short*)(wsb + 109051904);   // 117.4 MB -> ends 226.5 MB

    // 1. residual1 = hidden + residual ; h1 = rmsnorm(residual1) (bf16)
    add_rmsnorm_kernel<<<2048, 256, 0, stream>>>(hidden, residual, w_ln1, resid1, h1);
    // 2. qkv = h1 @ w_qkv^T  (f32 out)
    gemm_kernel<0><<<dim3(48, 16), 256, 0, stream>>>(h1, w_qkv, qkvbuf, nullptr, nullptr, 6144, 4096);
    // 3. RoPE -> q bf16, k bf16
    rope_kernel<<<dim3(40, 2048), 128, 0, stream>>>(positions, qkvbuf, qb, kb);
    // 4. V transpose -> vt bf16 [8][128][2048]
    vtrans_kernel<<<dim3(32, 8), 256, 0, stream>>>(qkvbuf, vt);
    // 5. flash attention -> ctx bf16 [2048][4096]
    flash_kernel<<<dim3(32, 32), 256, 0, stream>>>(qb, kb, vt, ctx);
    // 6. residual2 = ctx @ w_o^T + residual1  (writes d_out residual slot)
    gemm_kernel<1><<<dim3(32, 16), 256, 0, stream>>>(ctx, w_o, resid2, nullptr, resid1, 4096, 4096);
    // 7. h2 = rmsnorm(residual2) (bf16)
    add_rmsnorm_kernel<<<2048, 256, 0, stream>>>(resid2, nullptr, w_ln2, nullptr, h2);
    // 8. gu = h2 @ w_gate_up^T (bf16 out)
    gemm_kernel<2><<<dim3(224, 16), 256, 0, stream>>>(h2, w_gu, nullptr, gu, nullptr, 28672, 4096);
    // 9. hm = silu(gate)*up
    silu_kernel<<<dim3(7, 2048), 256, 0, stream>>>(gu, hm);
    // 10. out = hm @ w_down^T (f32, overwrites resid1 scratch)
    gemm_kernel<0><<<dim3(32, 16), 256, 0, stream>>>(hm, w_down, out_f, nullptr, nullptr, 4096, 14336);
}

// Round 2
// 1754.213 us; speedup vs baseline: 1.3415x; 1.3415x over previous
//
#include <hip/hip_runtime.h>

typedef short bf16x8 __attribute__((ext_vector_type(8)));
typedef short short4v __attribute__((ext_vector_type(4)));
typedef float f32x4 __attribute__((ext_vector_type(4)));

#define SCALE_ATTN 0.08838834764831845f

__device__ inline short f2bs(float f) {
    unsigned u = __builtin_bit_cast(unsigned, f);
    unsigned r = (u + 0x7fffu + ((u >> 16) & 1u)) >> 16;
    return (short)(unsigned short)r;
}
__device__ inline float b2f(short s) {
    unsigned u = ((unsigned)(unsigned short)s) << 16;
    return __builtin_bit_cast(float, u);
}
__device__ inline void pack_w(const float4& a, const float4& b, bf16x8& p) {
    p[0] = f2bs(a.x); p[1] = f2bs(a.y); p[2] = f2bs(a.z); p[3] = f2bs(a.w);
    p[4] = f2bs(b.x); p[5] = f2bs(b.y); p[6] = f2bs(b.z); p[7] = f2bs(b.w);
}

// ---------------------------------------------------------------------------
// weight convert f32 -> bf16 (RNE), 8 elems/thread, grid-stride
// ---------------------------------------------------------------------------
__global__ __launch_bounds__(256)
void wconv_kernel(const float* __restrict__ src, short* __restrict__ dst, long n8)
{
    const long stride = (long)gridDim.x << 8;
    for (long i = ((long)blockIdx.x << 8) + threadIdx.x; i < n8; i += stride) {
        const float4 a = ((const float4*)src)[i << 1];
        const float4 b = ((const float4*)src)[(i << 1) + 1];
        bf16x8 p;
        pack_w(a, b, p);
        ((bf16x8*)dst)[i] = p;
    }
}

// ---------------------------------------------------------------------------
// fused add + RMSNorm.  If Rin: sum = X+Rin, write sum (f32) to Rout.
// Writes bf16 normalized output to Hout.  One block per row of 4096.
// ---------------------------------------------------------------------------
__global__ __launch_bounds__(256)
void add_rmsnorm_kernel(const float* __restrict__ X, const float* __restrict__ Rin,
                        const float* __restrict__ w, float* __restrict__ Rout,
                        short* __restrict__ Hout)
{
    const int tid = threadIdx.x;
    const long base = (long)blockIdx.x << 12;
    float v[16];
    float ss = 0.f;
#pragma unroll
    for (int p = 0; p < 4; ++p) {
        const int idx = (p << 10) + (tid << 2);
        float4 a = *(const float4*)(X + base + idx);
        if (Rin != nullptr) {
            float4 b = *(const float4*)(Rin + base + idx);
            a.x += b.x; a.y += b.y; a.z += b.z; a.w += b.w;
        }
        v[p*4+0] = a.x; v[p*4+1] = a.y; v[p*4+2] = a.z; v[p*4+3] = a.w;
        ss += a.x*a.x + a.y*a.y + a.z*a.z + a.w*a.w;
    }
#pragma unroll
    for (int dd = 1; dd < 64; dd <<= 1) ss += __shfl_xor(ss, dd);
    __shared__ float red[4];
    if ((tid & 63) == 0) red[tid >> 6] = ss;
    __syncthreads();
    const float tot = red[0] + red[1] + red[2] + red[3];
    const float rstd = rsqrtf(tot * (1.0f / 4096.0f) + 1e-5f);
#pragma unroll
    for (int p = 0; p < 4; ++p) {
        const int idx = (p << 10) + (tid << 2);
        if (Rout != nullptr) {
            float4 b; b.x = v[p*4+0]; b.y = v[p*4+1]; b.z = v[p*4+2]; b.w = v[p*4+3];
            *(float4*)(Rout + base + idx) = b;
        }
        float4 wv4 = *(const float4*)(w + idx);
        short4v hb;
        hb[0] = f2bs(v[p*4+0] * rstd * wv4.x);
        hb[1] = f2bs(v[p*4+1] * rstd * wv4.y);
        hb[2] = f2bs(v[p*4+2] * rstd * wv4.z);
        hb[3] = f2bs(v[p*4+3] * rstd * wv4.w);
        *(short4v*)(Hout + base + idx) = hb;
    }
}

// ---------------------------------------------------------------------------
// m97-structure GEMM: C[M,N] = A[M,K](bf16) * W[N,K](bf16)
// 128x128 tile, BK=32, 4 waves of 64x64, global_load_lds(16B) staging,
// double-buffered linear LDS, 1 barrier/K-step, XCD-aware block swizzle.
// EPI 0: f32 store.  EPI 1: f32 store + resid add.  EPI 2: bf16 store.
// ---------------------------------------------------------------------------
#define STAGE(buf, kt) do {                                                         \
    const int _k0 = (kt) << 5;                                                      \
    _Pragma("unroll")                                                               \
    for (int _i = 0; _i < 2; ++_i) {                                                \
        const int _j = j0 + _i;                                                     \
        const short* _ga = A + (row0 + (_j << 4) + rA) * (long)K + _k0 + cA;        \
        __builtin_amdgcn_global_load_lds(                                           \
            (const __attribute__((address_space(1))) void*)(const void*)_ga,        \
            (__attribute__((address_space(3))) void*)(void*)&As[buf][_j << 9],      \
            16, 0, 0);                                                              \
        const short* _gw = W + (col0 + (_j << 4) + rA) * (long)K + _k0 + cA;        \
        __builtin_amdgcn_global_load_lds(                                           \
            (const __attribute__((address_space(1))) void*)(const void*)_gw,        \
            (__attribute__((address_space(3))) void*)(void*)&Ws[buf][_j << 9],      \
            16, 0, 0);                                                              \
    }                                                                               \
} while (0)

template<int EPI>
__global__ __launch_bounds__(256)
void gemm_bf16(const short* __restrict__ A, const short* __restrict__ W,
               float* __restrict__ Cf, short* __restrict__ Cb,
               const float* __restrict__ resid, int N, int K)
{
    __shared__ short As[2][4096];
    __shared__ short Ws[2][4096];
    const int tid  = threadIdx.x;
    const int lane = tid & 63;
    const int wv   = tid >> 6;
    const int l15  = lane & 15;
    const int l4e  = (lane >> 4) << 3;

    // XCD-aware bijective swizzle (all grids have nwg % 8 == 0)
    const int nwg  = gridDim.x * gridDim.y;
    const int cpx  = nwg >> 3;
    const int flat = blockIdx.y * gridDim.x + blockIdx.x;
    const int swzid = (flat & 7) * cpx + (flat >> 3);
    const int bx = swzid % gridDim.x;
    const int by = swzid / gridDim.x;

    const long row0 = (long)by << 7;
    const long col0 = (long)bx << 7;
    const int wr = (wv >> 1) << 6;
    const int wc = (wv & 1) << 6;

    const int rA = lane >> 2;          // 0..15: row within 16-row chunk
    const int cA = (lane & 3) << 3;    // 0,8,16,24: k-offset (bf16 elems)
    const int j0 = wv << 1;            // chunk base for this wave

    f32x4 acc[4][4];
#pragma unroll
    for (int i = 0; i < 4; ++i)
#pragma unroll
        for (int j = 0; j < 4; ++j) acc[i][j] = (f32x4){0.f,0.f,0.f,0.f};

    const int nk = K >> 5;

    STAGE(0, 0);
    __syncthreads();
    int cur = 0;
#pragma unroll 1
    for (int kt = 0; kt < nk; ++kt) {
        if (kt + 1 < nk) STAGE(cur ^ 1, kt + 1);
        bf16x8 af[4], bfr[4];
#pragma unroll
        for (int i = 0; i < 4; ++i)
            af[i] = *(const bf16x8*)&As[cur][(wr + i*16 + l15) * 32 + l4e];
#pragma unroll
        for (int j = 0; j < 4; ++j)
            bfr[j] = *(const bf16x8*)&Ws[cur][(wc + j*16 + l15) * 32 + l4e];
#pragma unroll
        for (int i = 0; i < 4; ++i)
#pragma unroll
            for (int j = 0; j < 4; ++j)
                acc[i][j] = __builtin_amdgcn_mfma_f32_16x16x32_bf16(af[i], bfr[j], acc[i][j], 0, 0, 0);
        __syncthreads();
        cur ^= 1;
    }

#pragma unroll
    for (int i = 0; i < 4; ++i) {
#pragma unroll
        for (int j = 0; j < 4; ++j) {
            const long gr = row0 + wr + i*16 + ((lane >> 4) << 2);
            const long gc = col0 + wc + j*16 + l15;
#pragma unroll
            for (int r = 0; r < 4; ++r) {
                const float v = acc[i][j][r];
                const long idx = (gr + r) * N + gc;
                if (EPI == 0)      Cf[idx] = v;
                else if (EPI == 1) Cf[idx] = v + resid[idx];
                else               Cb[idx] = f2bs(v);
            }
        }
    }
}

// ---------------------------------------------------------------------------
// RoPE: reads qkv f32 [S,6144]; writes roped q (bf16 [S,32,128]) and
// k (bf16 [S,8,128]).  grid (40, S), block 128.
// ---------------------------------------------------------------------------
__global__ __launch_bounds__(128)
void rope_kernel(const int* __restrict__ pos, const float* __restrict__ qkv,
                 short* __restrict__ Qo, short* __restrict__ Ko)
{
    const int h = blockIdx.x;
    const int s = blockIdx.y;
    const int d = threadIdx.x;
    const int j = d & 63;
    const float p = (float)pos[s];
    const float invf = __expf((float)j * -0.20503692895f);  // ln(5e5)/64
    float sn, cs;
    __sincosf(p * invf, &sn, &cs);
    const long base = (long)s * 6144 + h * 128;
    const float x1 = qkv[base + j];
    const float x2 = qkv[base + 64 + j];
    const float outv = (d < 64) ? (x1 * cs - x2 * sn) : (x2 * cs + x1 * sn);
    const short ob = f2bs(outv);
    if (h < 32) Qo[(long)s * 4096 + h * 128 + d] = ob;
    else        Ko[(long)s * 1024 + (h - 32) * 128 + d] = ob;
}

// ---------------------------------------------------------------------------
// V transpose: qkv f32 v-part [S,8,128] -> Vt bf16 [8][128][S]
// grid (S/64, 8), block 256.
// ---------------------------------------------------------------------------
__global__ __launch_bounds__(256)
void vtrans_kernel(const float* __restrict__ qkv, short* __restrict__ Vt)
{
    __shared__ short tile[64][136];
    const int tid = threadIdx.x;
    const int s0 = blockIdx.x << 6;
    const int h = blockIdx.y;
    {
        const int srow = tid >> 2;
        const int c0 = (tid & 3) << 5;
        const float* src = qkv + (long)(s0 + srow) * 6144 + 5120 + h * 128 + c0;
#pragma unroll
        for (int m = 0; m < 8; ++m) {
            float4 f = *(const float4*)(src + (m << 2));
            tile[srow][c0 + (m << 2) + 0] = f2bs(f.x);
            tile[srow][c0 + (m << 2) + 1] = f2bs(f.y);
            tile[srow][c0 + (m << 2) + 2] = f2bs(f.z);
            tile[srow][c0 + (m << 2) + 3] = f2bs(f.w);
        }
    }
    __syncthreads();
    {
        const int d = tid >> 1;
        const int sc = (tid & 1) << 5;
        short* dst = Vt + ((long)h * 128 + d) * 2048 + s0 + sc;
#pragma unroll
        for (int m = 0; m < 4; ++m) {
            bf16x8 v;
#pragma unroll
            for (int e = 0; e < 8; ++e) v[e] = tile[sc + (m << 3) + e][d];
            *(bf16x8*)(dst + (m << 3)) = v;
        }
    }
}

// ---------------------------------------------------------------------------
// Flash attention (causal, GQA rep=4).  grid (S/64 qtiles, 32 heads), 256 thr.
// 4 waves x 16 q-rows each; KV tiles of 64; XOR-swizzled LDS.
// ---------------------------------------------------------------------------
__global__ __launch_bounds__(256)
void flash_kernel(const short* __restrict__ Qg, const short* __restrict__ Kg,
                  const short* __restrict__ Vtg, short* __restrict__ Ctx)
{
    __shared__ short Qs[64 * 128];
    __shared__ short Ks[64 * 128];
    __shared__ short Vs[128 * 64];
    __shared__ short Ps[4 * 16 * 64];

    const int tid  = threadIdx.x;
    const int lane = tid & 63;
    const int wv   = tid >> 6;
    const int l15  = lane & 15;
    const int l4e  = (lane >> 4) << 3;
    const int qt   = blockIdx.x;
    const int head = blockIdx.y;
    const int q0   = qt << 6;
    const int kvh  = head >> 2;

    {   // stage Q (swizzled)
        const int row = tid >> 2;
        const int c0 = (tid & 3) << 5;
        const short* src = Qg + (long)(q0 + row) * 4096 + head * 128 + c0;
        const int sw = (row & 7) << 3;
#pragma unroll
        for (int m = 0; m < 4; ++m) {
            bf16x8 v = *(const bf16x8*)(src + (m << 3));
            *(bf16x8*)&Qs[row * 128 + ((c0 + (m << 3)) ^ sw)] = v;
        }
    }

    float mrow[4], lrow[4];
    f32x4 o[8];
#pragma unroll
    for (int r = 0; r < 4; ++r) { mrow[r] = -__builtin_inff(); lrow[r] = 0.f; }
#pragma unroll
    for (int d = 0; d < 8; ++d) o[d] = (f32x4){0.f,0.f,0.f,0.f};

    for (int t = 0; t <= qt; ++t) {
        const int kv0 = t << 6;
        __syncthreads();
        {   // stage K
            const int row = tid >> 2;
            const int c0 = (tid & 3) << 5;
            const short* src = Kg + (long)(kv0 + row) * 1024 + kvh * 128 + c0;
            const int sw = (row & 7) << 3;
#pragma unroll
            for (int m = 0; m < 4; ++m) {
                bf16x8 v = *(const bf16x8*)(src + (m << 3));
                *(bf16x8*)&Ks[row * 128 + ((c0 + (m << 3)) ^ sw)] = v;
            }
        }
        {   // stage Vt
            const int d = tid >> 1;
            const int c0 = (tid & 1) << 5;
            const short* src = Vtg + ((long)kvh * 128 + d) * 2048 + kv0 + c0;
            const int sw = (d & 7) << 3;
#pragma unroll
            for (int m = 0; m < 4; ++m) {
                bf16x8 v = *(const bf16x8*)(src + (m << 3));
                *(bf16x8*)&Vs[d * 64 + ((c0 + (m << 3)) ^ sw)] = v;
            }
        }
        __syncthreads();

        // QK^T : 16 q-rows x 64 kv-cols per wave
        bf16x8 qa[4];
        {
            const int qrow = (wv << 4) + l15;
            const int sw = (qrow & 7) << 3;
#pragma unroll
            for (int kk = 0; kk < 4; ++kk)
                qa[kk] = *(const bf16x8*)&Qs[qrow * 128 + ((l4e + (kk << 5)) ^ sw)];
        }
        f32x4 sacc[4];
#pragma unroll
        for (int j = 0; j < 4; ++j) {
            sacc[j] = (f32x4){0.f,0.f,0.f,0.f};
            const int krow = (j << 4) + l15;
            const int sw = (krow & 7) << 3;
#pragma unroll
            for (int kk = 0; kk < 4; ++kk) {
                bf16x8 kb8 = *(const bf16x8*)&Ks[krow * 128 + ((l4e + (kk << 5)) ^ sw)];
                sacc[j] = __builtin_amdgcn_mfma_f32_16x16x32_bf16(qa[kk], kb8, sacc[j], 0, 0, 0);
            }
        }

        // online softmax (rows live in 16-lane groups)
#pragma unroll
        for (int ri = 0; ri < 4; ++ri) {
            const int grow = q0 + (wv << 4) + ((lane >> 4) << 2) + ri;
            float sv[4];
#pragma unroll
            for (int j = 0; j < 4; ++j) {
                float s = sacc[j][ri] * SCALE_ATTN;
                const int col = kv0 + (j << 4) + l15;
                sv[j] = (col > grow) ? -1e30f : s;
            }
            float mx = fmaxf(fmaxf(sv[0], sv[1]), fmaxf(sv[2], sv[3]));
#pragma unroll
            for (int dd = 1; dd < 16; dd <<= 1) mx = fmaxf(mx, __shfl_xor(mx, dd));
            const float mnew = fmaxf(mrow[ri], mx);
            const float alpha = __expf(mrow[ri] - mnew);
            mrow[ri] = mnew;
            float psum = 0.f;
            short pb[4];
#pragma unroll
            for (int j = 0; j < 4; ++j) {
                float p = __expf(sv[j] - mnew);
                psum += p;
                pb[j] = f2bs(p);
            }
            lrow[ri] = lrow[ri] * alpha + psum;
#pragma unroll
            for (int d = 0; d < 8; ++d) o[d][ri] *= alpha;
            const int prow = ((lane >> 4) << 2) + ri;
            const int sw = (prow & 7) << 3;
#pragma unroll
            for (int j = 0; j < 4; ++j)
                Ps[(wv << 10) + prow * 64 + ((((j << 4) + l15)) ^ sw)] = pb[j];
        }

        // PV : P(16x64) x V(64x128)
        bf16x8 pa0, pa1;
        {
            const int prow = l15;
            const int sw = (prow & 7) << 3;
            pa0 = *(const bf16x8*)&Ps[(wv << 10) + prow * 64 + (l4e ^ sw)];
            pa1 = *(const bf16x8*)&Ps[(wv << 10) + prow * 64 + ((l4e + 32) ^ sw)];
        }
#pragma unroll
        for (int fd = 0; fd < 8; ++fd) {
            const int drow = (fd << 4) + l15;
            const int sw = (drow & 7) << 3;
            bf16x8 v0 = *(const bf16x8*)&Vs[drow * 64 + (l4e ^ sw)];
            bf16x8 v1 = *(const bf16x8*)&Vs[drow * 64 + ((l4e + 32) ^ sw)];
            o[fd] = __builtin_amdgcn_mfma_f32_16x16x32_bf16(pa0, v0, o[fd], 0, 0, 0);
            o[fd] = __builtin_amdgcn_mfma_f32_16x16x32_bf16(pa1, v1, o[fd], 0, 0, 0);
        }
    }

    float inv[4];
#pragma unroll
    for (int ri = 0; ri < 4; ++ri) {
        float ls = lrow[ri];
#pragma unroll
        for (int dd = 1; dd < 16; dd <<= 1) ls += __shfl_xor(ls, dd);
        inv[ri] = 1.0f / ls;
    }
#pragma unroll
    for (int fd = 0; fd < 8; ++fd)
#pragma unroll
        for (int ri = 0; ri < 4; ++ri) {
            const long row = q0 + (wv << 4) + ((lane >> 4) << 2) + ri;
            Ctx[row * 4096 + head * 128 + (fd << 4) + l15] = f2bs(o[fd][ri] * inv[ri]);
        }
}

// ---------------------------------------------------------------------------
// SiLU(gate)*up : gu bf16 [S, 28672] -> hm bf16 [S, 14336]
// grid (7, S), block 256, 8 elems/thread.
// ---------------------------------------------------------------------------
__global__ __launch_bounds__(256)
void silu_kernel(const short* __restrict__ gu, short* __restrict__ hm)
{
    const int s = blockIdx.y;
    const int j = ((blockIdx.x << 8) + threadIdx.x) << 3;
    const short* g = gu + (long)s * 28672 + j;
    bf16x8 gv = *(const bf16x8*)g;
    bf16x8 uv = *(const bf16x8*)(g + 14336);
    bf16x8 ov;
#pragma unroll
    for (int e = 0; e < 8; ++e) {
        const float gf = b2f(gv[e]);
        const float uf = b2f(uv[e]);
        const float r = gf / (1.f + __expf(-gf)) * uf;
        ov[e] = f2bs(r);
    }
    *(bf16x8*)(hm + (long)s * 14336 + j) = ov;
}

// ---------------------------------------------------------------------------
extern "C" void kernel_launch(void* const* d_in, const int* in_sizes, int n_in,
                              void* d_out, int out_size, void* d_ws, size_t ws_size,
                              hipStream_t stream)
{
    const int*   positions = (const int*)d_in[0];
    const float* hidden    = (const float*)d_in[1];
    const float* residual  = (const float*)d_in[2];
    const float* w_qkv     = (const float*)d_in[3];
    const float* w_o       = (const float*)d_in[4];
    const float* w_gu      = (const float*)d_in[5];
    const float* w_down    = (const float*)d_in[6];
    const float* w_ln1     = (const float*)d_in[7];
    const float* w_ln2     = (const float*)d_in[8];

    float* out_f   = (float*)d_out;              // [2048,4096] final output
    float* resid2  = out_f + 8388608;            // [2048,4096] residual output
    float* resid1  = out_f;                      // scratch: dead before down-GEMM writes

    char* wsb = (char*)d_ws;
    short* h1     = (short*)(wsb + 0);           // 16.8 MB (dead after qkv gemm)
    short* ctx    = (short*)(wsb + 0);           // reuse
    float* qkvbuf = (float*)(wsb + 16777216);    // 50.3 MB f32 (dead after rope/vtrans)
    short* h2     = (short*)(wsb + 16777216);    // reuse (16.8 MB)
    short* qb     = (short*)(wsb + 67108864);    // 16.8 MB (dead after flash)
    short* kb     = (short*)(wsb + 83886080);    //  4.2 MB (dead after flash)
    short* vt     = (short*)(wsb + 88080384);    //  4.2 MB (dead after flash)
    short* gu     = (short*)(wsb + 33554432);    // 117.4 MB, ends 151.0 MB (over dead qkv/qb/kb/vt)
    short* hm     = (short*)(wsb + 150994944);   // 58.7 MB, ends 209.7 MB
    short* wbuf   = (short*)(wsb + 209715200);   // 235 MB slab for current bf16 weight -> ends ~424 MB

    // 1. residual1 = hidden + residual ; h1 = rmsnorm(residual1) (bf16)
    add_rmsnorm_kernel<<<2048, 256, 0, stream>>>(hidden, residual, w_ln1, resid1, h1);
    // 2. qkv weight -> bf16 ; qkv = h1 @ w_qkv^T (f32 out)
    wconv_kernel<<<2048, 256, 0, stream>>>(w_qkv, wbuf, 3145728L);
    gemm_bf16<0><<<dim3(48, 16), 256, 0, stream>>>(h1, wbuf, qkvbuf, nullptr, nullptr, 6144, 4096);
    // 3. RoPE -> q bf16, k bf16
    rope_kernel<<<dim3(40, 2048), 128, 0, stream>>>(positions, qkvbuf, qb, kb);
    // 4. V transpose -> vt bf16 [8][128][2048]
    vtrans_kernel<<<dim3(32, 8), 256, 0, stream>>>(qkvbuf, vt);
    // 5. flash attention -> ctx bf16 [2048][4096]
    flash_kernel<<<dim3(32, 32), 256, 0, stream>>>(qb, kb, vt, ctx);
    // 6. o weight -> bf16 ; residual2 = ctx @ w_o^T + residual1
    wconv_kernel<<<2048, 256, 0, stream>>>(w_o, wbuf, 2097152L);
    gemm_bf16<1><<<dim3(32, 16), 256, 0, stream>>>(ctx, wbuf, resid2, nullptr, resid1, 4096, 4096);
    // 7. h2 = rmsnorm(residual2) (bf16)
    add_rmsnorm_kernel<<<2048, 256, 0, stream>>>(resid2, nullptr, w_ln2, nullptr, h2);
    // 8. gate_up weight -> bf16 ; gu = h2 @ w_gate_up^T (bf16 out)
    wconv_kernel<<<2048, 256, 0, stream>>>(w_gu, wbuf, 14680064L);
    gemm_bf16<2><<<dim3(224, 16), 256, 0, stream>>>(h2, wbuf, nullptr, gu, nullptr, 28672, 4096);
    // 9. hm = silu(gate)*up
    silu_kernel<<<dim3(7, 2048), 256, 0, stream>>>(gu, hm);
    // 10. down weight -> bf16 ; out = hm @ w_down^T (f32, overwrites resid1 scratch)
    wconv_kernel<<<2048, 256, 0, stream>>>(w_down, wbuf, 7340032L);
    gemm_bf16<0><<<dim3(32, 16), 256, 0, stream>>>(hm, wbuf, out_f, nullptr, nullptr, 4096, 14336);
}

// Round 3
// 1577.613 us; speedup vs baseline: 1.4916x; 1.1119x over previous
//
#include <hip/hip_runtime.h>

typedef short bf16x8 __attribute__((ext_vector_type(8)));
typedef short short4v __attribute__((ext_vector_type(4)));
typedef float f32x4 __attribute__((ext_vector_type(4)));

#define SCALE_ATTN 0.08838834764831845f

__device__ inline short f2bs(float f) {
    unsigned u = __builtin_bit_cast(unsigned, f);
    unsigned r = (u + 0x7fffu + ((u >> 16) & 1u)) >> 16;
    return (short)(unsigned short)r;
}
__device__ inline float b2f(short s) {
    unsigned u = ((unsigned)(unsigned short)s) << 16;
    return __builtin_bit_cast(float, u);
}
__device__ inline void pack_w(const float4& a, const float4& b, bf16x8& p) {
    p[0] = f2bs(a.x); p[1] = f2bs(a.y); p[2] = f2bs(a.z); p[3] = f2bs(a.w);
    p[4] = f2bs(b.x); p[5] = f2bs(b.y); p[6] = f2bs(b.z); p[7] = f2bs(b.w);
}

// ---------------------------------------------------------------------------
// weight convert f32 -> bf16 (RNE), 8 elems/thread, grid-stride
// ---------------------------------------------------------------------------
__global__ __launch_bounds__(256)
void wconv_kernel(const float* __restrict__ src, short* __restrict__ dst, long n8)
{
    const long stride = (long)gridDim.x << 8;
    for (long i = ((long)blockIdx.x << 8) + threadIdx.x; i < n8; i += stride) {
        const float4 a = ((const float4*)src)[i << 1];
        const float4 b = ((const float4*)src)[(i << 1) + 1];
        bf16x8 p;
        pack_w(a, b, p);
        ((bf16x8*)dst)[i] = p;
    }
}

// ---------------------------------------------------------------------------
// fused add + RMSNorm
// ---------------------------------------------------------------------------
__global__ __launch_bounds__(256)
void add_rmsnorm_kernel(const float* __restrict__ X, const float* __restrict__ Rin,
                        const float* __restrict__ w, float* __restrict__ Rout,
                        short* __restrict__ Hout)
{
    const int tid = threadIdx.x;
    const long base = (long)blockIdx.x << 12;
    float v[16];
    float ss = 0.f;
#pragma unroll
    for (int p = 0; p < 4; ++p) {
        const int idx = (p << 10) + (tid << 2);
        float4 a = *(const float4*)(X + base + idx);
        if (Rin != nullptr) {
            float4 b = *(const float4*)(Rin + base + idx);
            a.x += b.x; a.y += b.y; a.z += b.z; a.w += b.w;
        }
        v[p*4+0] = a.x; v[p*4+1] = a.y; v[p*4+2] = a.z; v[p*4+3] = a.w;
        ss += a.x*a.x + a.y*a.y + a.z*a.z + a.w*a.w;
    }
#pragma unroll
    for (int dd = 1; dd < 64; dd <<= 1) ss += __shfl_xor(ss, dd);
    __shared__ float red[4];
    if ((tid & 63) == 0) red[tid >> 6] = ss;
    __syncthreads();
    const float tot = red[0] + red[1] + red[2] + red[3];
    const float rstd = rsqrtf(tot * (1.0f / 4096.0f) + 1e-5f);
#pragma unroll
    for (int p = 0; p < 4; ++p) {
        const int idx = (p << 10) + (tid << 2);
        if (Rout != nullptr) {
            float4 b; b.x = v[p*4+0]; b.y = v[p*4+1]; b.z = v[p*4+2]; b.w = v[p*4+3];
            *(float4*)(Rout + base + idx) = b;
        }
        float4 wv4 = *(const float4*)(w + idx);
        short4v hb;
        hb[0] = f2bs(v[p*4+0] * rstd * wv4.x);
        hb[1] = f2bs(v[p*4+1] * rstd * wv4.y);
        hb[2] = f2bs(v[p*4+2] * rstd * wv4.z);
        hb[3] = f2bs(v[p*4+3] * rstd * wv4.w);
        *(short4v*)(Hout + base + idx) = hb;
    }
}

// ===========================================================================
// 8-phase 256x256 GEMM (T2 swizzle + T3/T4 counted vmcnt + T5 setprio)
// C[M,N] = A[M,K](bf16) * W[N,K](bf16).  512 thr = 8 waves (2M x 4N),
// BK=64, 2 K-tiles per iter, LDS 128 KiB double-buffered.
// ===========================================================================
#define BAR()   do { asm volatile("" ::: "memory"); __builtin_amdgcn_s_barrier(); asm volatile("" ::: "memory"); } while (0)
#define LGKM0() asm volatile("s_waitcnt lgkmcnt(0)" ::: "memory")
#define VMW(n)  asm volatile("s_waitcnt vmcnt(" #n ")" ::: "memory")

__device__ inline bf16x8 lds_frag(const short* tile, int row, int kb) {
    const int off = row * 128 + (kb ^ ((row & 7) << 4));
    return *(const bf16x8*)((const char*)tile + off);
}

// stage one half-tile (128 rows x 64 k) of G[N/M rows][K] into LDS (linear
// dest, inverse-swizzled source).  2 x global_load_lds(16B) per wave.
__device__ inline void stage_half(const short* __restrict__ G, long grow0, long K,
                                  long k0, short* ldsHalf, int wv, int lane)
{
#pragma unroll
    for (int i = 0; i < 2; ++i) {
        short* dst = ldsHalf + ((i << 13) + (wv << 10)) / 2;   // wave-uniform
        const int off = (wv << 10) + (i << 13) + (lane << 4);  // this lane's byte slot
        const int r   = off >> 7;
        const int cb  = off & 127;
        const int gcb = cb ^ ((r & 7) << 4);
        const short* src = G + (grow0 + r) * K + k0 + (gcb >> 1);
        __builtin_amdgcn_global_load_lds(
            (const __attribute__((address_space(1))) void*)(const void*)src,
            (__attribute__((address_space(3))) void*)(void*)dst, 16, 0, 0);
    }
}

#define LOAD_A(T, grp) do {                                        \
    _Pragma("unroll") for (int _m = 0; _m < 4; ++_m) {             \
        const int _row = abase + (grp)*64 + _m*16 + l15;           \
        a[_m][0] = lds_frag(T, _row, l4b);                         \
        a[_m][1] = lds_frag(T, _row, 64 + l4b);                    \
    } } while (0)

#define LOAD_B(T, n0) do {                                         \
    _Pragma("unroll") for (int _n = 0; _n < 2; ++_n) {             \
        const int _row = bbase + ((n0)+_n)*16 + l15;               \
        b[(n0)+_n][0] = lds_frag(T, _row, l4b);                    \
        b[(n0)+_n][1] = lds_frag(T, _row, 64 + l4b);               \
    } } while (0)

#define MFMA16(MB, NB) do {                                                        \
    __builtin_amdgcn_s_setprio(1);                                                 \
    _Pragma("unroll") for (int _m = 0; _m < 4; ++_m)                               \
    _Pragma("unroll") for (int _n = 0; _n < 2; ++_n) {                             \
        acc[(MB)+_m][(NB)+_n] = __builtin_amdgcn_mfma_f32_16x16x32_bf16(           \
            a[_m][0], b[(NB)+_n][0], acc[(MB)+_m][(NB)+_n], 0, 0, 0);              \
        acc[(MB)+_m][(NB)+_n] = __builtin_amdgcn_mfma_f32_16x16x32_bf16(           \
            a[_m][1], b[(NB)+_n][1], acc[(MB)+_m][(NB)+_n], 0, 0, 0);              \
    }                                                                              \
    __builtin_amdgcn_s_setprio(0);                                                 \
} while (0)

template<int EPI>
__global__ __launch_bounds__(512, 2)
void gemm8(const short* __restrict__ A, const short* __restrict__ W,
           float* __restrict__ Cf, short* __restrict__ Cb,
           const float* __restrict__ resid, int N, int K)
{
    __shared__ __align__(16) short As[2][16384];
    __shared__ __align__(16) short Bs[2][16384];

    const int tid  = threadIdx.x;
    const int lane = tid & 63;
    const int wv   = tid >> 6;
    const int wm   = wv >> 2;          // 0..1
    const int wn   = wv & 3;           // 0..3
    const int l15  = lane & 15;
    const int l4b  = (lane >> 4) << 4; // byte k-offset 0,16,32,48

    // XCD swizzle: column-major within XCD -> 8 consecutive same-XCD blocks
    // share one weight panel (gy is always 8 = M blocks).
    const int nwg  = gridDim.x << 3;
    const int cpx  = nwg >> 3;
    const int orig = (blockIdx.y * gridDim.x) + blockIdx.x;
    const int lgc  = (orig & 7) * cpx + (orig >> 3);
    const int bx   = lgc >> 3;
    const int by   = lgc & 7;

    const long row0 = (long)by << 8;
    const long col0 = (long)bx << 8;
    const int abase = wm << 7;
    const int bbase = wn << 6;

    f32x4 acc[8][4];
#pragma unroll
    for (int i = 0; i < 8; ++i)
#pragma unroll
        for (int j = 0; j < 4; ++j) acc[i][j] = (f32x4){0.f,0.f,0.f,0.f};

    bf16x8 a[4][2], b[4][2];
    const int iters = K >> 7;

    // prologue: stage tiles 0 (buf0) and 1 (buf1)
    stage_half(A, row0,       K, 0,  &As[0][0],    wv, lane);
    stage_half(A, row0 + 128, K, 0,  &As[0][8192], wv, lane);
    stage_half(W, col0,       K, 0,  &Bs[0][0],    wv, lane);
    stage_half(W, col0 + 128, K, 0,  &Bs[0][8192], wv, lane);
    stage_half(A, row0,       K, 64, &As[1][0],    wv, lane);
    stage_half(A, row0 + 128, K, 64, &As[1][8192], wv, lane);
    stage_half(W, col0,       K, 64, &Bs[1][0],    wv, lane);
    stage_half(W, col0 + 128, K, 64, &Bs[1][8192], wv, lane);
    VMW(8);
    BAR();

#pragma unroll 1
    for (int it = 0; it < iters; ++it) {
        const long k2 = ((long)(2*it + 2)) << 6;
        const long k3 = k2 + 64;
        const bool pf = (it + 1 < iters);

        // ---------------- tile 2it (buf0) ----------------
        // P1
        LOAD_A(As[0], 0); LOAD_B(Bs[0], 0);
        BAR(); LGKM0(); MFMA16(0, 0); BAR();
        // P2
        LOAD_B(Bs[0], 2);
        BAR(); LGKM0(); MFMA16(0, 2); BAR();
        // P3
        LOAD_A(As[0], 1);
        if (pf) stage_half(W, col0, K, k2, &Bs[0][0], wv, lane);          // B0(t+2)
        BAR(); LGKM0(); MFMA16(4, 0); BAR();
        // P4
        if (pf) {
            stage_half(A, row0,       K, k2, &As[0][0],    wv, lane);     // A0(t+2)
            stage_half(W, col0 + 128, K, k2, &Bs[0][8192], wv, lane);     // B1(t+2)
        }
        VMW(6);
        BAR(); MFMA16(4, 2); BAR();

        // ---------------- tile 2it+1 (buf1) ----------------
        // P5
        LOAD_A(As[1], 0); LOAD_B(Bs[1], 0);
        if (pf) stage_half(A, row0 + 128, K, k2, &As[0][8192], wv, lane); // A1(t+2)
        BAR(); LGKM0(); MFMA16(0, 0); BAR();
        // P6
        LOAD_B(Bs[1], 2);
        BAR(); LGKM0(); MFMA16(0, 2); BAR();
        // P7
        LOAD_A(As[1], 1);
        if (pf) {
            stage_half(W, col0,       K, k3, &Bs[1][0],    wv, lane);     // B0(t+3)
            stage_half(W, col0 + 128, K, k3, &Bs[1][8192], wv, lane);     // B1(t+3)
        }
        BAR(); LGKM0(); MFMA16(4, 0); BAR();
        // P8
        if (pf) {
            stage_half(A, row0,       K, k3, &As[1][0],    wv, lane);     // A0(t+3)
            stage_half(A, row0 + 128, K, k3, &As[1][8192], wv, lane);     // A1(t+3)
        }
        VMW(8);
        BAR(); MFMA16(4, 2); BAR();
    }

    // epilogue
#pragma unroll
    for (int m = 0; m < 8; ++m) {
#pragma unroll
        for (int n = 0; n < 4; ++n) {
            const long gr = row0 + (wm << 7) + m*16 + ((lane >> 4) << 2);
            const long gc = col0 + (wn << 6) + n*16 + l15;
#pragma unroll
            for (int r = 0; r < 4; ++r) {
                const float v = acc[m][n][r];
                const long idx = (gr + r) * N + gc;
                if (EPI == 0)      Cf[idx] = v;
                else if (EPI == 1) Cf[idx] = v + resid[idx];
                else               Cb[idx] = f2bs(v);
            }
        }
    }
}

// ---------------------------------------------------------------------------
// RoPE
// ---------------------------------------------------------------------------
__global__ __launch_bounds__(128)
void rope_kernel(const int* __restrict__ pos, const float* __restrict__ qkv,
                 short* __restrict__ Qo, short* __restrict__ Ko)
{
    const int h = blockIdx.x;
    const int s = blockIdx.y;
    const int d = threadIdx.x;
    const int j = d & 63;
    const float p = (float)pos[s];
    const float invf = __expf((float)j * -0.20503692895f);  // ln(5e5)/64
    float sn, cs;
    __sincosf(p * invf, &sn, &cs);
    const long base = (long)s * 6144 + h * 128;
    const float x1 = qkv[base + j];
    const float x2 = qkv[base + 64 + j];
    const float outv = (d < 64) ? (x1 * cs - x2 * sn) : (x2 * cs + x1 * sn);
    const short ob = f2bs(outv);
    if (h < 32) Qo[(long)s * 4096 + h * 128 + d] = ob;
    else        Ko[(long)s * 1024 + (h - 32) * 128 + d] = ob;
}

// ---------------------------------------------------------------------------
// V transpose: qkv f32 v-part [S,8,128] -> Vt bf16 [8][128][S]
// ---------------------------------------------------------------------------
__global__ __launch_bounds__(256)
void vtrans_kernel(const float* __restrict__ qkv, short* __restrict__ Vt)
{
    __shared__ short tile[64][136];
    const int tid = threadIdx.x;
    const int s0 = blockIdx.x << 6;
    const int h = blockIdx.y;
    {
        const int srow = tid >> 2;
        const int c0 = (tid & 3) << 5;
        const float* src = qkv + (long)(s0 + srow) * 6144 + 5120 + h * 128 + c0;
#pragma unroll
        for (int m = 0; m < 8; ++m) {
            float4 f = *(const float4*)(src + (m << 2));
            tile[srow][c0 + (m << 2) + 0] = f2bs(f.x);
            tile[srow][c0 + (m << 2) + 1] = f2bs(f.y);
            tile[srow][c0 + (m << 2) + 2] = f2bs(f.z);
            tile[srow][c0 + (m << 2) + 3] = f2bs(f.w);
        }
    }
    __syncthreads();
    {
        const int d = tid >> 1;
        const int sc = (tid & 1) << 5;
        short* dst = Vt + ((long)h * 128 + d) * 2048 + s0 + sc;
#pragma unroll
        for (int m = 0; m < 4; ++m) {
            bf16x8 v;
#pragma unroll
            for (int e = 0; e < 8; ++e) v[e] = tile[sc + (m << 3) + e][d];
            *(bf16x8*)(dst + (m << 3)) = v;
        }
    }
}

// ---------------------------------------------------------------------------
// Flash attention (causal, GQA rep=4)
// ---------------------------------------------------------------------------
__global__ __launch_bounds__(256)
void flash_kernel(const short* __restrict__ Qg, const short* __restrict__ Kg,
                  const short* __restrict__ Vtg, short* __restrict__ Ctx)
{
    __shared__ short Qs[64 * 128];
    __shared__ short Ks[64 * 128];
    __shared__ short Vs[128 * 64];
    __shared__ short Ps[4 * 16 * 64];

    const int tid  = threadIdx.x;
    const int lane = tid & 63;
    const int wv   = tid >> 6;
    const int l15  = lane & 15;
    const int l4e  = (lane >> 4) << 3;
    const int qt   = blockIdx.x;
    const int head = blockIdx.y;
    const int q0   = qt << 6;
    const int kvh  = head >> 2;

    {   // stage Q (swizzled)
        const int row = tid >> 2;
        const int c0 = (tid & 3) << 5;
        const short* src = Qg + (long)(q0 + row) * 4096 + head * 128 + c0;
        const int sw = (row & 7) << 3;
#pragma unroll
        for (int m = 0; m < 4; ++m) {
            bf16x8 v = *(const bf16x8*)(src + (m << 3));
            *(bf16x8*)&Qs[row * 128 + ((c0 + (m << 3)) ^ sw)] = v;
        }
    }

    float mrow[4], lrow[4];
    f32x4 o[8];
#pragma unroll
    for (int r = 0; r < 4; ++r) { mrow[r] = -__builtin_inff(); lrow[r] = 0.f; }
#pragma unroll
    for (int d = 0; d < 8; ++d) o[d] = (f32x4){0.f,0.f,0.f,0.f};

    for (int t = 0; t <= qt; ++t) {
        const int kv0 = t << 6;
        __syncthreads();
        {   // stage K
            const int row = tid >> 2;
            const int c0 = (tid & 3) << 5;
            const short* src = Kg + (long)(kv0 + row) * 1024 + kvh * 128 + c0;
            const int sw = (row & 7) << 3;
#pragma unroll
            for (int m = 0; m < 4; ++m) {
                bf16x8 v = *(const bf16x8*)(src + (m << 3));
                *(bf16x8*)&Ks[row * 128 + ((c0 + (m << 3)) ^ sw)] = v;
            }
        }
        {   // stage Vt
            const int d = tid >> 1;
            const int c0 = (tid & 1) << 5;
            const short* src = Vtg + ((long)kvh * 128 + d) * 2048 + kv0 + c0;
            const int sw = (d & 7) << 3;
#pragma unroll
            for (int m = 0; m < 4; ++m) {
                bf16x8 v = *(const bf16x8*)(src + (m << 3));
                *(bf16x8*)&Vs[d * 64 + ((c0 + (m << 3)) ^ sw)] = v;
            }
        }
        __syncthreads();

        bf16x8 qa[4];
        {
            const int qrow = (wv << 4) + l15;
            const int sw = (qrow & 7) << 3;
#pragma unroll
            for (int kk = 0; kk < 4; ++kk)
                qa[kk] = *(const bf16x8*)&Qs[qrow * 128 + ((l4e + (kk << 5)) ^ sw)];
        }
        f32x4 sacc[4];
#pragma unroll
        for (int j = 0; j < 4; ++j) {
            sacc[j] = (f32x4){0.f,0.f,0.f,0.f};
            const int krow = (j << 4) + l15;
            const int sw = (krow & 7) << 3;
#pragma unroll
            for (int kk = 0; kk < 4; ++kk) {
                bf16x8 kb8 = *(const bf16x8*)&Ks[krow * 128 + ((l4e + (kk << 5)) ^ sw)];
                sacc[j] = __builtin_amdgcn_mfma_f32_16x16x32_bf16(qa[kk], kb8, sacc[j], 0, 0, 0);
            }
        }

#pragma unroll
        for (int ri = 0; ri < 4; ++ri) {
            const int grow = q0 + (wv << 4) + ((lane >> 4) << 2) + ri;
            float sv[4];
#pragma unroll
            for (int j = 0; j < 4; ++j) {
                float s = sacc[j][ri] * SCALE_ATTN;
                const int col = kv0 + (j << 4) + l15;
                sv[j] = (col > grow) ? -1e30f : s;
            }
            float mx = fmaxf(fmaxf(sv[0], sv[1]), fmaxf(sv[2], sv[3]));
#pragma unroll
            for (int dd = 1; dd < 16; dd <<= 1) mx = fmaxf(mx, __shfl_xor(mx, dd));
            const float mnew = fmaxf(mrow[ri], mx);
            const float alpha = __expf(mrow[ri] - mnew);
            mrow[ri] = mnew;
            float psum = 0.f;
            short pb[4];
#pragma unroll
            for (int j = 0; j < 4; ++j) {
                float p = __expf(sv[j] - mnew);
                psum += p;
                pb[j] = f2bs(p);
            }
            lrow[ri] = lrow[ri] * alpha + psum;
#pragma unroll
            for (int d = 0; d < 8; ++d) o[d][ri] *= alpha;
            const int prow = ((lane >> 4) << 2) + ri;
            const int sw = (prow & 7) << 3;
#pragma unroll
            for (int j = 0; j < 4; ++j)
                Ps[(wv << 10) + prow * 64 + ((((j << 4) + l15)) ^ sw)] = pb[j];
        }

        bf16x8 pa0, pa1;
        {
            const int prow = l15;
            const int sw = (prow & 7) << 3;
            pa0 = *(const bf16x8*)&Ps[(wv << 10) + prow * 64 + (l4e ^ sw)];
            pa1 = *(const bf16x8*)&Ps[(wv << 10) + prow * 64 + ((l4e + 32) ^ sw)];
        }
#pragma unroll
        for (int fd = 0; fd < 8; ++fd) {
            const int drow = (fd << 4) + l15;
            const int sw = (drow & 7) << 3;
            bf16x8 v0 = *(const bf16x8*)&Vs[drow * 64 + (l4e ^ sw)];
            bf16x8 v1 = *(const bf16x8*)&Vs[drow * 64 + ((l4e + 32) ^ sw)];
            o[fd] = __builtin_amdgcn_mfma_f32_16x16x32_bf16(pa0, v0, o[fd], 0, 0, 0);
            o[fd] = __builtin_amdgcn_mfma_f32_16x16x32_bf16(pa1, v1, o[fd], 0, 0, 0);
        }
    }

    float inv[4];
#pragma unroll
    for (int ri = 0; ri < 4; ++ri) {
        float ls = lrow[ri];
#pragma unroll
        for (int dd = 1; dd < 16; dd <<= 1) ls += __shfl_xor(ls, dd);
        inv[ri] = 1.0f / ls;
    }
#pragma unroll
    for (int fd = 0; fd < 8; ++fd)
#pragma unroll
        for (int ri = 0; ri < 4; ++ri) {
            const long row = q0 + (wv << 4) + ((lane >> 4) << 2) + ri;
            Ctx[row * 4096 + head * 128 + (fd << 4) + l15] = f2bs(o[fd][ri] * inv[ri]);
        }
}

// ---------------------------------------------------------------------------
// SiLU(gate)*up
// ---------------------------------------------------------------------------
__global__ __launch_bounds__(256)
void silu_kernel(const short* __restrict__ gu, short* __restrict__ hm)
{
    const int s = blockIdx.y;
    const int j = ((blockIdx.x << 8) + threadIdx.x) << 3;
    const short* g = gu + (long)s * 28672 + j;
    bf16x8 gv = *(const bf16x8*)g;
    bf16x8 uv = *(const bf16x8*)(g + 14336);
    bf16x8 ov;
#pragma unroll
    for (int e = 0; e < 8; ++e) {
        const float gf = b2f(gv[e]);
        const float uf = b2f(uv[e]);
        const float r = gf / (1.f + __expf(-gf)) * uf;
        ov[e] = f2bs(r);
    }
    *(bf16x8*)(hm + (long)s * 14336 + j) = ov;
}

// ---------------------------------------------------------------------------
extern "C" void kernel_launch(void* const* d_in, const int* in_sizes, int n_in,
                              void* d_out, int out_size, void* d_ws, size_t ws_size,
                              hipStream_t stream)
{
    const int*   positions = (const int*)d_in[0];
    const float* hidden    = (const float*)d_in[1];
    const float* residual  = (const float*)d_in[2];
    const float* w_qkv     = (const float*)d_in[3];
    const float* w_o       = (const float*)d_in[4];
    const float* w_gu      = (const float*)d_in[5];
    const float* w_down    = (const float*)d_in[6];
    const float* w_ln1     = (const float*)d_in[7];
    const float* w_ln2     = (const float*)d_in[8];

    float* out_f   = (float*)d_out;              // [2048,4096] final output
    float* resid2  = out_f + 8388608;            // [2048,4096] residual output
    float* resid1  = out_f;                      // scratch: dead before down-GEMM writes

    char* wsb = (char*)d_ws;
    short* h1     = (short*)(wsb + 0);           // 16.8 MB (dead after qkv gemm)
    short* ctx    = (short*)(wsb + 0);           // reuse
    float* qkvbuf = (float*)(wsb + 16777216);    // 50.3 MB f32 (dead after rope/vtrans)
    short* h2     = (short*)(wsb + 16777216);    // reuse (16.8 MB)
    short* qb     = (short*)(wsb + 67108864);    // 16.8 MB (dead after flash)
    short* kb     = (short*)(wsb + 83886080);    //  4.2 MB (dead after flash)
    short* vt     = (short*)(wsb + 88080384);    //  4.2 MB (dead after flash)
    short* gu     = (short*)(wsb + 33554432);    // 117.4 MB, ends 151.0 MB
    short* hm     = (short*)(wsb + 150994944);   // 58.7 MB, ends 209.7 MB
    short* wbuf   = (short*)(wsb + 209715200);   // 235 MB slab -> ends ~424 MB

    // 1. residual1 = hidden + residual ; h1 = rmsnorm(residual1) (bf16)
    add_rmsnorm_kernel<<<2048, 256, 0, stream>>>(hidden, residual, w_ln1, resid1, h1);
    // 2. qkv weight -> bf16 ; qkv = h1 @ w_qkv^T (f32 out)
    wconv_kernel<<<2048, 256, 0, stream>>>(w_qkv, wbuf, 3145728L);
    gemm8<0><<<dim3(24, 8), 512, 0, stream>>>(h1, wbuf, qkvbuf, nullptr, nullptr, 6144, 4096);
    // 3. RoPE -> q bf16, k bf16
    rope_kernel<<<dim3(40, 2048), 128, 0, stream>>>(positions, qkvbuf, qb, kb);
    // 4. V transpose -> vt bf16 [8][128][2048]
    vtrans_kernel<<<dim3(32, 8), 256, 0, stream>>>(qkvbuf, vt);
    // 5. flash attention -> ctx bf16 [2048][4096]
    flash_kernel<<<dim3(32, 32), 256, 0, stream>>>(qb, kb, vt, ctx);
    // 6. o weight -> bf16 ; residual2 = ctx @ w_o^T + residual1
    wconv_kernel<<<2048, 256, 0, stream>>>(w_o, wbuf, 2097152L);
    gemm8<1><<<dim3(16, 8), 512, 0, stream>>>(ctx, wbuf, resid2, nullptr, resid1, 4096, 4096);
    // 7. h2 = rmsnorm(residual2) (bf16)
    add_rmsnorm_kernel<<<2048, 256, 0, stream>>>(resid2, nullptr, w_ln2, nullptr, h2);
    // 8. gate_up weight -> bf16 ; gu = h2 @ w_gate_up^T (bf16 out)
    wconv_kernel<<<2048, 256, 0, stream>>>(w_gu, wbuf, 14680064L);
    gemm8<2><<<dim3(112, 8), 512, 0, stream>>>(h2, wbuf, nullptr, gu, nullptr, 28672, 4096);
    // 9. hm = silu(gate)*up
    silu_kernel<<<dim3(7, 2048), 256, 0, stream>>>(gu, hm);
    // 10. down weight -> bf16 ; out = hm @ w_down^T (f32, overwrites resid1 scratch)
    wconv_kernel<<<2048, 256, 0, stream>>>(w_down, wbuf, 7340032L);
    gemm8<0><<<dim3(16, 8), 512, 0, stream>>>(hm, wbuf, out_f, nullptr, nullptr, 4096, 14336);
}